// Round 11
// baseline (150.444 us; speedup 1.0000x reference)
//
#include <hip/hip_runtime.h>
#include <hip/hip_bf16.h>
#include <stdint.h>

// Problem constants (B, L, D, T) = (2, 2048, 1536, 2)
#define B_ 2
#define L_ 2048
#define D_ 1536

typedef __attribute__((ext_vector_type(4))) float  f32x4;
typedef __attribute__((ext_vector_type(8))) __bf16 bf16x8;

__device__ __forceinline__ unsigned short f2bf(float f) {
  unsigned int u = __float_as_uint(f);
  u += 0x7fffu + ((u >> 16) & 1u);   // RNE
  return (unsigned short)(u >> 16);
}

// ---------------------------------------------------------------------------
// Stage 1: hs(fp32) -> X(bf16), and P[t] = hs * Wp[t] (bf16), t in {0,1}
// ---------------------------------------------------------------------------
__global__ __launch_bounds__(256) void conv_kernel(
    const float* __restrict__ hs, const float* __restrict__ W,
    unsigned short* __restrict__ X, unsigned short* __restrict__ P) {
  const int idx  = blockIdx.x * 256 + threadIdx.x;
  const int base = idx * 4;
  const int d    = base % D_;
  const float4 h  = *(const float4*)(hs + base);
  const float4 w0 = *(const float4*)(W + d);
  const float4 w1 = *(const float4*)(W + 2 * D_ + d);
  ushort4 x, p0, p1;
  x.x  = f2bf(h.x);        x.y  = f2bf(h.y);        x.z  = f2bf(h.z);        x.w  = f2bf(h.w);
  p0.x = f2bf(h.x * w0.x); p0.y = f2bf(h.y * w0.y); p0.z = f2bf(h.z * w0.z); p0.w = f2bf(h.w * w0.w);
  p1.x = f2bf(h.x * w1.x); p1.y = f2bf(h.y * w1.y); p1.z = f2bf(h.z * w1.z); p1.w = f2bf(h.w * w1.w);
  *(ushort4*)(X + base) = x;
  *(ushort4*)(P + base) = p0;
  *(ushort4*)(P + (size_t)B_ * L_ * D_ + base) = p1;
}

// ---------------------------------------------------------------------------
// Stage 2 redesign: 128x128 block (M = 64 i x 2 t), 256 thr = 4 waves (2x2
// of 64x64), 48 K-slices of BK=32, 3 LDS buffers x 16 KB = 48 KB ->
// 3 BLOCKS/CU (12 waves, three independent barrier domains). Rationale:
// r8-r10 showed per-slice time = SUM(LDS,MFMA) pipes; 244/256 regs at the
// 256-tile blocks any intra-wave overlap (no frag dbuf headroom), and one
// barrier domain at 2 waves/SIMD gives weak cross-wave overlap. Smaller acc
// (64 AGPR) + 3 co-resident blocks let other blocks' waves feed the MFMA
// pipe during a block's read-burst/barrier, and hide epilogues (1024 blocks
// = 4 generations/CU). Pipeline: mod-3 rotation, stage distance 2, counted
// vmcnt(4) (never drains in loop); stage placed after RDALL / before MFMA
// (r8-verified placement; r9/r10 alternatives measured -5 us each).
// M layout [t0 i0-31 | t1 i0-31 | t0 i32-63 | t1 i32-63] so each wave holds
// (t0,t1) at the same i -> dense float2 epilogue. Sub-block layout, XOR
// swizzle, fragment/C-D mappings verbatim from r8 (0 conflicts verified).
// ---------------------------------------------------------------------------
__device__ __forceinline__ void gload16(const unsigned short* g, unsigned short* l) {
  __builtin_amdgcn_global_load_lds(
      (const __attribute__((address_space(1))) unsigned int*)g,
      (__attribute__((address_space(3))) unsigned int*)l, 16, 0, 0);
}

#define B0O 0
#define B1O 8192
#define B2O 16384

__global__ __launch_bounds__(256, 3) void gemm_kernel(
    const unsigned short* __restrict__ X, const unsigned short* __restrict__ P,
    const float* __restrict__ bias, float2* __restrict__ out) {
  __shared__ unsigned short lds[24576];   // 48 KiB = 3 buffers x 8192 shorts

  const int tid = threadIdx.x;

  // ---- T1: XCD-aware bijective swizzle (1024 % 8 == 0); consecutive
  // within-XCD ids share the A panel (J sweeps fastest).
  const int id  = blockIdx.x;
  const int swz = (id & 7) * 128 + (id >> 3);
  const int bz  = swz >> 9;               // batch
  const int t2  = swz & 511;
  const int I0  = (t2 >> 4) * 64;         // 32 i-tiles of 64
  const int J0  = (t2 & 15) * 128;        // 16 j-tiles of 128

  const size_t planeB = (size_t)B_ * L_ * D_;

  // ---- staging: region = 128 rows x 32 shorts (64 B rows, 4 chunk slots).
  // Entry e = tid + 256*l: row r = e>>2, slot s = e&3; stored chunk
  // c = s ^ ((r>>1)&3)  ((r>>1)&3 == (tid>>3)&3 for both l). LDS dest is
  // linear: e*16 B = tid*8 shorts (+2048 for l1) -> wave-uniform + lane*16.
  // A rows (l0): M-rows 0-63 = [t0 i0-31 | t1 i0-31]: plane = tid>>7,
  //   i = I0 + (tid>>2)&31;  l1 = M-rows 64-127: same plane, i + 32.
  // B rows: j = J0 + (tid>>2) (l0), +64 (l1).
  const int    csrc = (((tid & 3) ^ ((tid >> 3) & 3))) * 8;
  const unsigned short* pA0 = P + (size_t)(tid >> 7) * planeB +
                              (size_t)(bz * L_ + I0 + ((tid >> 2) & 31)) * D_ + csrc;
  const unsigned short* pA1 = pA0 + (size_t)32 * D_;
  const unsigned short* pB0 = X + (size_t)(bz * L_ + J0 + (tid >> 2)) * D_ + csrc;
  const unsigned short* pB1 = pB0 + (size_t)64 * D_;

  // ---- compute geometry: 4 waves as 2x2 (wr x wc), wave tile 64M x 64N
  const int lane = tid & 63;
  const int w    = tid >> 6;
  const int wr   = w & 1;
  const int wc   = w >> 1;
  const int lr   = lane & 15;
  const int q    = lane >> 4;
  const int slot8 = (q ^ ((lr >> 1) & 3)) * 8;   // read-side swizzled slot
  int aOff[4], bOff[4];
#pragma unroll
  for (int m = 0; m < 4; ++m) aOff[m] = (wr * 64 + m * 16 + lr) * 32;
#pragma unroll
  for (int n = 0; n < 4; ++n) bOff[n] = 4096 + (wc * 64 + n * 16 + lr) * 32;

  f32x4  acc[4][4] = {};   // 64 AGPRs
  bf16x8 aF[4], bF[4];

#define STG(NB, PN)                                                           \
  do {                                                                        \
    const size_t ko = (size_t)((PN) * 32);                                    \
    gload16(pA0 + ko, lds + (NB) + tid * 8);                                  \
    gload16(pA1 + ko, lds + (NB) + 2048 + tid * 8);                           \
    gload16(pB0 + ko, lds + (NB) + 4096 + tid * 8);                           \
    gload16(pB1 + ko, lds + (NB) + 6144 + tid * 8);                           \
  } while (0)

#define RDALL(CB)                                                             \
  do {                                                                        \
    const unsigned short* base_ = lds + (CB) + slot8;                         \
    _Pragma("unroll") for (int m = 0; m < 4; ++m)                             \
      aF[m] = *(const bf16x8*)(base_ + aOff[m]);                              \
    _Pragma("unroll") for (int n = 0; n < 4; ++n)                             \
      bF[n] = *(const bf16x8*)(base_ + bOff[n]);                              \
  } while (0)

#define MMALL()                                                               \
  do {                                                                        \
    _Pragma("unroll") for (int m = 0; m < 4; ++m)                             \
      _Pragma("unroll") for (int n = 0; n < 4; ++n)                           \
        acc[m][n] = __builtin_amdgcn_mfma_f32_16x16x32_bf16(                  \
            aF[m], bF[n], acc[m][n], 0, 0, 0);                                \
  } while (0)

#define WVM(n)  asm volatile("s_waitcnt vmcnt(" #n ")" ::: "memory")
#define BARS()                                                                \
  do {                                                                        \
    __builtin_amdgcn_s_barrier();                                             \
    __builtin_amdgcn_sched_barrier(0);                                        \
  } while (0)
#define PRIO1() __builtin_amdgcn_s_setprio(1)
#define PRIO0() __builtin_amdgcn_s_setprio(0)

  // phase p: read buf p%3, stage slice p+2 into buf (p+2)%3 (freed at p-1,
  // confirmed by the p-1 barrier), MFMA, wait slice p+1 (vmcnt 4: leaves
  // p+2's 4 loads in flight), barrier.
#define PH(CB, SB, PN)                                                        \
  do {                                                                        \
    RDALL(CB);                                                                \
    STG(SB, PN);                                                              \
    PRIO1(); MMALL(); PRIO0();                                                \
    WVM(4); BARS();                                                           \
  } while (0)

  // ---- prologue: slices 0,1 into buffers 0,1
  STG(B0O, 0);
  STG(B1O, 1);
  WVM(4);   // slice 0 resident
  BARS();

  // ---- main loop: phases 0..44 (15 x 3), then peeled 45,46,47
#pragma unroll 1
  for (int it = 0; it < 15; ++it) {
    const int p0 = 3 * it;
    PH(B0O, B2O, p0 + 2);
    PH(B1O, B0O, p0 + 3);
    PH(B2O, B1O, p0 + 4);
  }
  // p=45: read b0, stage 47 -> b2
  RDALL(B0O); STG(B2O, 47);
  PRIO1(); MMALL(); PRIO0();
  WVM(4); BARS();
  // p=46: read b1
  RDALL(B1O);
  PRIO1(); MMALL(); PRIO0();
  WVM(0); BARS();
  // p=47: read b2
  RDALL(B2O);
  PRIO1(); MMALL(); PRIO0();

#undef PH
#undef STG
#undef RDALL
#undef MMALL

  // ---- epilogue: C/D col(j)=lane&15, row(i)=q*4+reg (r8-verified mapping).
  // frag m (m<2) = t0, frag m+2 = t1 at the SAME i -> dense float2.
  const float bias0 = bias[0], bias1 = bias[1];
#pragma unroll
  for (int m = 0; m < 2; ++m) {
#pragma unroll
    for (int r = 0; r < 4; ++r) {
      const int i = I0 + wr * 32 + m * 16 + q * 4 + r;
      float2* orow = out + (size_t)(bz * L_ + i) * L_ + (J0 + wc * 64 + lr);
#pragma unroll
      for (int n = 0; n < 4; ++n) {
        float2 v;
        v.x = acc[m][n][r] + bias0;
        v.y = acc[m + 2][n][r] + bias1;
        orow[n * 16] = v;
      }
    }
  }
}

extern "C" void kernel_launch(void* const* d_in, const int* in_sizes, int n_in,
                              void* d_out, int out_size, void* d_ws, size_t ws_size,
                              hipStream_t stream) {
  const float* hs   = (const float*)d_in[0];
  const float* W    = (const float*)d_in[1];
  const float* bias = (const float*)d_in[2];

  unsigned short* X = (unsigned short*)d_ws;                 // B*L*D bf16
  unsigned short* P = X + (size_t)B_ * L_ * D_;              // T*B*L*D bf16

  const int nconv = (B_ * L_ * D_ / 4) / 256;                // 6144 blocks
  conv_kernel<<<nconv, 256, 0, stream>>>(hs, W, X, P);

  gemm_kernel<<<1024, 256, 0, stream>>>(X, P, bias, (float2*)d_out);
}